// Round 1
// baseline (256.460 us; speedup 1.0000x reference)
//
#include <hip/hip_runtime.h>
#include <hip/hip_bf16.h>
#include <stdint.h>

#define Bn 8
#define Sn 4096
#define Hn 768
#define Dn 1024
#define Wn 2048

typedef __attribute__((ext_vector_type(8))) short short8;
typedef __attribute__((ext_vector_type(4))) float floatx4;

__device__ __forceinline__ void load_lds16(const void* g, void* l) {
  __builtin_amdgcn_global_load_lds(
      (const __attribute__((address_space(1))) void*)g,
      (__attribute__((address_space(3))) void*)l, 16, 0, 0);
}

// ---------------- kernel 1: proj_w (H x D fp32) -> B^T (D x H bf16) -------------
__global__ __launch_bounds__(256) void k_transpose(const float* __restrict__ pw,
                                                   __hip_bfloat16* __restrict__ wb) {
  __shared__ float tile[32][33];
  const int d0 = blockIdx.x * 32, h0 = blockIdx.y * 32;
  const int tx = threadIdx.x, ty = threadIdx.y;  // (32, 8)
#pragma unroll
  for (int i = 0; i < 32; i += 8)
    tile[ty + i][tx] = pw[(size_t)(h0 + ty + i) * Dn + d0 + tx];
  __syncthreads();
#pragma unroll
  for (int i = 0; i < 32; i += 8)
    wb[(size_t)(d0 + ty + i) * Hn + h0 + tx] = (__hip_bfloat16)tile[tx][ty + i];
}

// ------------- kernel 2: segment mean + validity mask ---------------------------
// grid = (Wn, Bn), block = 256. word_ids sorted per batch -> contiguous ranges.
__global__ __launch_bounds__(256) void k_words(const float* __restrict__ emb,
                                               const int* __restrict__ masks,
                                               const int* __restrict__ wid,
                                               __hip_bfloat16* __restrict__ wa,
                                               float* __restrict__ out_masks) {
  const int w = blockIdx.x, b = blockIdx.y;
  const int* widb = wid + (size_t)b * Sn;

  // lower bound of w
  int lo = 0, hi = Sn;
  while (lo < hi) { int mid = (lo + hi) >> 1; if (widb[mid] < w) lo = mid + 1; else hi = mid; }
  const int start = lo;
  // upper bound of w
  hi = Sn;
  while (lo < hi) { int mid = (lo + hi) >> 1; if (widb[mid] <= w) lo = mid + 1; else hi = mid; }
  const int end = lo;

  const int count = end - start;
  int mcount = 0;
  const int* mb = masks + (size_t)b * Sn;
  for (int s = start; s < end; ++s) mcount += mb[s];
  const bool valid = (count > 0) && (count == mcount);
  const float inv = valid ? 1.0f / (float)count : 0.0f;

  const int t = threadIdx.x;
  const size_t rowbase = ((size_t)b * Wn + w) * Hn;
#pragma unroll
  for (int j = 0; j < 3; ++j) {
    const int h = t + j * 256;
    float sum = 0.f;
    for (int s = start; s < end; ++s)
      sum += emb[((size_t)b * Sn + s) * Hn + h];
    wa[rowbase + h] = (__hip_bfloat16)(sum * inv);
  }
  if (t == 0) out_masks[(size_t)b * Wn + w] = valid ? 1.0f : 0.0f;
}

// ------------- kernel 3: bf16 MFMA GEMM  C = A @ B + bias -----------------------
// A: (M=16384, K=768) bf16, Bt: (N=1024, K=768) bf16, C: fp32.
// 128x128 block tile, BK=32, 4 waves each 64x64 (4x4 of 16x16x32 MFMA).
__global__ __launch_bounds__(256) void k_gemm(const short* __restrict__ A,
                                              const short* __restrict__ Bt,
                                              const float* __restrict__ bias,
                                              float* __restrict__ out) {
  constexpr int K = Hn;   // 768
  constexpr int N = Dn;   // 1024
  __shared__ __align__(16) short lsA[128 * 32];
  __shared__ __align__(16) short lsB[128 * 32];

  const int t = threadIdx.x;
  const int lane = t & 63, wave = t >> 6;
  const int wm = wave >> 1, wn = wave & 1;
  const int lane16 = lane & 15, quad = lane >> 4;
  const int m0 = blockIdx.y * 128, n0 = blockIdx.x * 128;

  // staging map: thread t loads 16B at rows t/4 and t/4+64, col (t%4)*8.
  // LDS offset = row*32 + col elems = wave_base + lane*16 bytes (lane-contiguous).
  const int lrow = t >> 2;
  const int lcol = (t & 3) * 8;
  const short* gA0 = A + (size_t)(m0 + lrow) * K + lcol;
  const short* gB0 = Bt + (size_t)(n0 + lrow) * K + lcol;
  short* lA0 = &lsA[lrow * 32 + lcol];
  short* lB0 = &lsB[lrow * 32 + lcol];

  floatx4 acc[4][4];
#pragma unroll
  for (int i = 0; i < 4; ++i)
#pragma unroll
    for (int j = 0; j < 4; ++j) acc[i][j] = (floatx4){0.f, 0.f, 0.f, 0.f};

  for (int k0 = 0; k0 < K; k0 += 32) {
    load_lds16(gA0 + k0, lA0);
    load_lds16(gA0 + (size_t)64 * K + k0, lA0 + 64 * 32);
    load_lds16(gB0 + k0, lB0);
    load_lds16(gB0 + (size_t)64 * K + k0, lB0 + 64 * 32);
    __syncthreads();

    short8 af[4], bf[4];
#pragma unroll
    for (int mi = 0; mi < 4; ++mi)
      af[mi] = *(const short8*)&lsA[(wm * 64 + mi * 16 + lane16) * 32 + quad * 8];
#pragma unroll
    for (int ni = 0; ni < 4; ++ni)
      bf[ni] = *(const short8*)&lsB[(wn * 64 + ni * 16 + lane16) * 32 + quad * 8];

#pragma unroll
    for (int mi = 0; mi < 4; ++mi)
#pragma unroll
      for (int ni = 0; ni < 4; ++ni)
        acc[mi][ni] = __builtin_amdgcn_mfma_f32_16x16x32_bf16(af[mi], bf[ni], acc[mi][ni], 0, 0, 0);
    __syncthreads();
  }

  // epilogue: C/D layout col = lane&15, row = quad*4 + r  (m89/m91-verified)
#pragma unroll
  for (int mi = 0; mi < 4; ++mi) {
#pragma unroll
    for (int ni = 0; ni < 4; ++ni) {
      const int n = n0 + wn * 64 + ni * 16 + lane16;
      const float bv = bias[n];
#pragma unroll
      for (int r = 0; r < 4; ++r) {
        const int m = m0 + wm * 64 + mi * 16 + quad * 4 + r;
        out[(size_t)m * N + n] = acc[mi][ni][r] + bv;
      }
    }
  }
}

extern "C" void kernel_launch(void* const* d_in, const int* in_sizes, int n_in,
                              void* d_out, int out_size, void* d_ws, size_t ws_size,
                              hipStream_t stream) {
  const float* emb    = (const float*)d_in[0];  // (8, 4096, 768)
  const float* proj_w = (const float*)d_in[1];  // (768, 1024)
  const float* proj_b = (const float*)d_in[2];  // (1024,)
  const int*   masks  = (const int*)d_in[3];    // (8, 4096)
  const int*   wid    = (const int*)d_in[4];    // (8, 4096)

  float* out = (float*)d_out;                       // (8, 2048, 1024) fp32
  float* out_masks = out + (size_t)Bn * Wn * Dn;    // (8, 2048) as 0.0/1.0

  __hip_bfloat16* wb = (__hip_bfloat16*)d_ws;            // B^T: (1024, 768) bf16
  __hip_bfloat16* wa = wb + (size_t)Dn * Hn;             // A:   (16384, 768) bf16

  // 1. transpose + bf16-convert proj_w
  dim3 g1(Dn / 32, Hn / 32), b1(32, 8);
  k_transpose<<<g1, b1, 0, stream>>>(proj_w, wb);

  // 2. segment means + masks
  dim3 g2(Wn, Bn);
  k_words<<<g2, 256, 0, stream>>>(emb, masks, wid, wa, out_masks);

  // 3. projection GEMM + bias
  dim3 g3(Dn / 128, (Bn * Wn) / 128);  // (8, 128)
  k_gemm<<<g3, 256, 0, stream>>>((const short*)wa, (const short*)wb, proj_b, out);
}

// Round 2
// 224.206 us; speedup vs baseline: 1.1439x; 1.1439x over previous
//
#include <hip/hip_runtime.h>
#include <hip/hip_bf16.h>
#include <stdint.h>

#define Bn 8
#define Sn 4096
#define Hn 768
#define Dn 1024
#define Wn 2048

typedef __attribute__((ext_vector_type(8))) short short8;
typedef __attribute__((ext_vector_type(4))) short short4v;
typedef __attribute__((ext_vector_type(4))) float floatx4;

__device__ __forceinline__ void load_lds16(const void* g, void* l) {
  __builtin_amdgcn_global_load_lds(
      (const __attribute__((address_space(1))) void*)g,
      (__attribute__((address_space(3))) void*)l, 16, 0, 0);
}

// ---------------- kernel 1: proj_w (H x D fp32) -> B^T (D x H bf16) -------------
__global__ __launch_bounds__(256) void k_transpose(const float* __restrict__ pw,
                                                   __hip_bfloat16* __restrict__ wb) {
  __shared__ float tile[32][33];
  const int d0 = blockIdx.x * 32, h0 = blockIdx.y * 32;
  const int tx = threadIdx.x, ty = threadIdx.y;  // (32, 8)
#pragma unroll
  for (int i = 0; i < 32; i += 8)
    tile[ty + i][tx] = pw[(size_t)(h0 + ty + i) * Dn + d0 + tx];
  __syncthreads();
#pragma unroll
  for (int i = 0; i < 32; i += 8)
    wb[(size_t)(d0 + ty + i) * Hn + h0 + tx] = (__hip_bfloat16)tile[tx][ty + i];
}

// ---------------- kernel 1b: word boundary table --------------------------------
// word_ids sorted per batch. starts[b][w] = first s with wid[b][s] >= w;
// starts[b][Wn] = Sn. Every entry written exactly once (0xAA-poisoned ws!).
__global__ __launch_bounds__(256) void k_bounds(const int* __restrict__ wid,
                                                int* __restrict__ starts) {
  const int b = blockIdx.y;
  const int s = blockIdx.x * 256 + threadIdx.x;
  const int* wb = wid + (size_t)b * Sn;
  int* sb = starts + b * (Wn + 1);
  const int cur = wb[s];
  const int prev = (s == 0) ? -1 : wb[s - 1];
  for (int ww = prev + 1; ww <= cur; ++ww) sb[ww] = s;
  if (s == Sn - 1)
    for (int ww = cur + 1; ww <= Wn; ++ww) sb[ww] = Sn;
}

// ------------- kernel 2: segment mean + validity mask ---------------------------
// One wave per word (4 words per 256-thread block). No searches: boundaries
// come from the precomputed table; emb rows read float4-coalesced.
__global__ __launch_bounds__(256) void k_words(const float* __restrict__ emb,
                                               const int* __restrict__ masks,
                                               const int* __restrict__ starts,
                                               __hip_bfloat16* __restrict__ wa,
                                               float* __restrict__ out_masks) {
  const int b = blockIdx.y;
  const int wave = threadIdx.x >> 6, lane = threadIdx.x & 63;
  const int w = blockIdx.x * 4 + wave;

  const int* sb = starts + b * (Wn + 1);
  const int start = sb[w];
  const int end = sb[w + 1];
  const int count = end - start;

  int mcount = 0;
  const int* mb = masks + (size_t)b * Sn;
  for (int s = start; s < end; ++s) mcount += mb[s];  // same addr all lanes: broadcast
  const bool valid = (count > 0) && (count == mcount);
  const float inv = valid ? 1.0f / (float)count : 0.0f;

  floatx4 sum[3] = {{0.f, 0.f, 0.f, 0.f}, {0.f, 0.f, 0.f, 0.f}, {0.f, 0.f, 0.f, 0.f}};
  const float* eb = emb + (size_t)b * Sn * Hn;
  for (int s = start; s < end; ++s) {
    const floatx4* row = (const floatx4*)(eb + (size_t)s * Hn);
#pragma unroll
    for (int j = 0; j < 3; ++j) sum[j] += row[j * 64 + lane];
  }

  const size_t rowbase = ((size_t)b * Wn + w) * Hn;
#pragma unroll
  for (int j = 0; j < 3; ++j) {
    short4v o;
#pragma unroll
    for (int c = 0; c < 4; ++c) {
      __hip_bfloat16 h = (__hip_bfloat16)(sum[j][c] * inv);
      o[c] = *reinterpret_cast<short*>(&h);
    }
    *(short4v*)&wa[rowbase + (size_t)(j * 64 + lane) * 4] = o;
  }
  if (lane == 0) out_masks[(size_t)b * Wn + w] = valid ? 1.0f : 0.0f;
}

// ------------- kernel 3: bf16 MFMA GEMM  C = A @ B + bias -----------------------
// A: (M=16384, K=768) bf16, Bt: (N=1024, K=768) bf16, C: fp32.
// 128x128 block tile, BK=32, 4 waves each 64x64 (4x4 of 16x16x32 MFMA).
__global__ __launch_bounds__(256) void k_gemm(const short* __restrict__ A,
                                              const short* __restrict__ Bt,
                                              const float* __restrict__ bias,
                                              float* __restrict__ out) {
  constexpr int K = Hn;   // 768
  constexpr int N = Dn;   // 1024
  __shared__ __align__(16) short lsA[128 * 32];
  __shared__ __align__(16) short lsB[128 * 32];

  const int t = threadIdx.x;
  const int lane = t & 63, wave = t >> 6;
  const int wm = wave >> 1, wn = wave & 1;
  const int lane16 = lane & 15, quad = lane >> 4;
  const int m0 = blockIdx.y * 128, n0 = blockIdx.x * 128;

  // staging map: thread t loads 16B at rows t/4 and t/4+64, col (t%4)*8.
  // LDS offset = row*32 + col elems = wave_base + lane*16 bytes (lane-contiguous).
  const int lrow = t >> 2;
  const int lcol = (t & 3) * 8;
  const short* gA0 = A + (size_t)(m0 + lrow) * K + lcol;
  const short* gB0 = Bt + (size_t)(n0 + lrow) * K + lcol;
  short* lA0 = &lsA[lrow * 32 + lcol];
  short* lB0 = &lsB[lrow * 32 + lcol];

  floatx4 acc[4][4];
#pragma unroll
  for (int i = 0; i < 4; ++i)
#pragma unroll
    for (int j = 0; j < 4; ++j) acc[i][j] = (floatx4){0.f, 0.f, 0.f, 0.f};

  for (int k0 = 0; k0 < K; k0 += 32) {
    load_lds16(gA0 + k0, lA0);
    load_lds16(gA0 + (size_t)64 * K + k0, lA0 + 64 * 32);
    load_lds16(gB0 + k0, lB0);
    load_lds16(gB0 + (size_t)64 * K + k0, lB0 + 64 * 32);
    __syncthreads();

    short8 af[4], bf[4];
#pragma unroll
    for (int mi = 0; mi < 4; ++mi)
      af[mi] = *(const short8*)&lsA[(wm * 64 + mi * 16 + lane16) * 32 + quad * 8];
#pragma unroll
    for (int ni = 0; ni < 4; ++ni)
      bf[ni] = *(const short8*)&lsB[(wn * 64 + ni * 16 + lane16) * 32 + quad * 8];

#pragma unroll
    for (int mi = 0; mi < 4; ++mi)
#pragma unroll
      for (int ni = 0; ni < 4; ++ni)
        acc[mi][ni] = __builtin_amdgcn_mfma_f32_16x16x32_bf16(af[mi], bf[ni], acc[mi][ni], 0, 0, 0);
    __syncthreads();
  }

  // epilogue: C/D layout col = lane&15, row = quad*4 + r  (m89/m91-verified)
#pragma unroll
  for (int mi = 0; mi < 4; ++mi) {
#pragma unroll
    for (int ni = 0; ni < 4; ++ni) {
      const int n = n0 + wn * 64 + ni * 16 + lane16;
      const float bv = bias[n];
#pragma unroll
      for (int r = 0; r < 4; ++r) {
        const int m = m0 + wm * 64 + mi * 16 + quad * 4 + r;
        out[(size_t)m * N + n] = acc[mi][ni][r] + bv;
      }
    }
  }
}

extern "C" void kernel_launch(void* const* d_in, const int* in_sizes, int n_in,
                              void* d_out, int out_size, void* d_ws, size_t ws_size,
                              hipStream_t stream) {
  const float* emb    = (const float*)d_in[0];  // (8, 4096, 768)
  const float* proj_w = (const float*)d_in[1];  // (768, 1024)
  const float* proj_b = (const float*)d_in[2];  // (1024,)
  const int*   masks  = (const int*)d_in[3];    // (8, 4096)
  const int*   wid    = (const int*)d_in[4];    // (8, 4096)

  float* out = (float*)d_out;                       // (8, 2048, 1024) fp32
  float* out_masks = out + (size_t)Bn * Wn * Dn;    // (8, 2048) as 0.0/1.0

  __hip_bfloat16* wb = (__hip_bfloat16*)d_ws;            // B^T: (1024, 768) bf16
  __hip_bfloat16* wa = wb + (size_t)Dn * Hn;             // A:   (16384, 768) bf16
  int* starts = (int*)(wa + (size_t)Bn * Wn * Hn);       // (8, 2049) boundaries

  // 1. transpose + bf16-convert proj_w
  dim3 g1(Dn / 32, Hn / 32), b1(32, 8);
  k_transpose<<<g1, b1, 0, stream>>>(proj_w, wb);

  // 1b. word boundary table
  dim3 gb(Sn / 256, Bn);
  k_bounds<<<gb, 256, 0, stream>>>(wid, starts);

  // 2. segment means + masks (one wave per word)
  dim3 g2(Wn / 4, Bn);
  k_words<<<g2, 256, 0, stream>>>(emb, masks, starts, wa, out_masks);

  // 3. projection GEMM + bias
  dim3 g3(Dn / 128, (Bn * Wn) / 128);  // (8, 128)
  k_gemm<<<g3, 256, 0, stream>>>((const short*)wa, (const short*)wb, proj_b, out);
}

// Round 3
// 210.865 us; speedup vs baseline: 1.2162x; 1.0633x over previous
//
#include <hip/hip_runtime.h>
#include <hip/hip_bf16.h>
#include <stdint.h>

#define Bn 8
#define Sn 4096
#define Hn 768
#define Dn 1024
#define Wn 2048

typedef __attribute__((ext_vector_type(8))) short short8;
typedef __attribute__((ext_vector_type(4))) short short4v;
typedef __attribute__((ext_vector_type(4))) float floatx4;

__device__ __forceinline__ void load_lds16(const void* g, void* l) {
  __builtin_amdgcn_global_load_lds(
      (const __attribute__((address_space(1))) void*)g,
      (__attribute__((address_space(3))) void*)l, 16, 0, 0);
}

// -------- kernel 1: fused prep --------------------------------------------------
// blocks [0, 768): transpose proj_w (H x D fp32) -> B^T (D x H bf16), 32x32 tiles
// blocks [768, 896): boundary table starts[b][w] from sorted word_ids
__global__ __launch_bounds__(256) void k_prep(const float* __restrict__ pw,
                                              const int* __restrict__ wid,
                                              __hip_bfloat16* __restrict__ wb,
                                              int* __restrict__ starts) {
  if (blockIdx.x < 768) {
    __shared__ float tile[32][33];
    const int bt = blockIdx.x;            // 32 x 24 tile grid
    const int d0 = (bt % 32) * 32, h0 = (bt / 32) * 32;
    const int tx = threadIdx.x & 31, ty = threadIdx.x >> 5;  // 32 x 8
#pragma unroll
    for (int i = 0; i < 32; i += 8)
      tile[ty + i][tx] = pw[(size_t)(h0 + ty + i) * Dn + d0 + tx];
    __syncthreads();
#pragma unroll
    for (int i = 0; i < 32; i += 8)
      wb[(size_t)(d0 + ty + i) * Hn + h0 + tx] = (__hip_bfloat16)tile[tx][ty + i];
  } else {
    const int bid = blockIdx.x - 768;       // 128 blocks cover (Bn, Sn)
    const int g = bid * 256 + threadIdx.x;  // 0 .. 32767
    const int b = g >> 12, s = g & (Sn - 1);
    const int* wbi = wid + (size_t)b * Sn;
    int* sb = starts + b * (Wn + 1);
    const int cur = wbi[s];
    const int prev = (s == 0) ? -1 : wbi[s - 1];
    for (int ww = prev + 1; ww <= cur; ++ww) sb[ww] = s;
    if (s == Sn - 1)
      for (int ww = cur + 1; ww <= Wn; ++ww) sb[ww] = Sn;
  }
}

// ------------- kernel 2: segment mean + validity mask ---------------------------
// One wave per word (4 words per 256-thread block).
__global__ __launch_bounds__(256) void k_words(const float* __restrict__ emb,
                                               const int* __restrict__ masks,
                                               const int* __restrict__ starts,
                                               __hip_bfloat16* __restrict__ wa,
                                               float* __restrict__ out_masks) {
  const int b = blockIdx.y;
  const int wave = threadIdx.x >> 6, lane = threadIdx.x & 63;
  const int w = blockIdx.x * 4 + wave;

  const int* sb = starts + b * (Wn + 1);
  const int start = sb[w];
  const int end = sb[w + 1];
  const int count = end - start;

  // parallel all-ones mask check (one 64-lane load per 64 subwords)
  const int* mb = masks + (size_t)b * Sn;
  bool allone = true;
  for (int s0 = start; s0 < end; s0 += 64) {
    const int idx = s0 + lane;
    allone = allone && ((idx < end) ? (mb[idx] == 1) : true);
  }
  const bool valid = (count > 0) && __all(allone);
  const float inv = valid ? 1.0f / (float)count : 0.0f;

  floatx4 sum[3] = {{0.f, 0.f, 0.f, 0.f}, {0.f, 0.f, 0.f, 0.f}, {0.f, 0.f, 0.f, 0.f}};
  const float* eb = emb + (size_t)b * Sn * Hn;
  int s = start;
  for (; s + 1 < end; s += 2) {
    const floatx4* r0 = (const floatx4*)(eb + (size_t)s * Hn);
    const floatx4* r1 = (const floatx4*)(eb + (size_t)(s + 1) * Hn);
#pragma unroll
    for (int j = 0; j < 3; ++j) sum[j] += r0[j * 64 + lane];
#pragma unroll
    for (int j = 0; j < 3; ++j) sum[j] += r1[j * 64 + lane];
  }
  if (s < end) {
    const floatx4* r0 = (const floatx4*)(eb + (size_t)s * Hn);
#pragma unroll
    for (int j = 0; j < 3; ++j) sum[j] += r0[j * 64 + lane];
  }

  const size_t rowbase = ((size_t)b * Wn + w) * Hn;
#pragma unroll
  for (int j = 0; j < 3; ++j) {
    short4v o;
#pragma unroll
    for (int c = 0; c < 4; ++c) {
      __hip_bfloat16 h = (__hip_bfloat16)(sum[j][c] * inv);
      o[c] = *reinterpret_cast<short*>(&h);
    }
    *(short4v*)&wa[rowbase + (size_t)(j * 64 + lane) * 4] = o;
  }
  if (lane == 0) out_masks[(size_t)b * Wn + w] = valid ? 1.0f : 0.0f;
}

// ------------- kernel 3: bf16 MFMA GEMM  C = A @ B + bias -----------------------
// A: (M=16384, K=768) bf16, Bt: (N=1024, K=768) bf16, C: fp32.
// 128x128 block tile, BK=32, 4 waves each 64x64 (4x4 of 16x16x32 MFMA).
// XCD-aware swizzle: HW assigns XCD = blockIdx % 8 (round-robin). Give each XCD
// a strip of 16 m-tiles x all 8 n-tiles, n fastest, so the 8 blocks sharing an
// A-tile run consecutively on ONE XCD -> A-tile stays in that XCD's L2
// (A HBM traffic 192 MB -> 24 MB).
__global__ __launch_bounds__(256) void k_gemm(const short* __restrict__ A,
                                              const short* __restrict__ Bt,
                                              const float* __restrict__ bias,
                                              float* __restrict__ out) {
  constexpr int K = Hn;   // 768
  constexpr int N = Dn;   // 1024
  __shared__ __align__(16) short lsA[128 * 32];
  __shared__ __align__(16) short lsB[128 * 32];

  const int t = threadIdx.x;
  const int lane = t & 63, wave = t >> 6;
  const int wm = wave >> 1, wn = wave & 1;
  const int lane16 = lane & 15, quad = lane >> 4;

  const int linear = blockIdx.x;          // 1024 blocks
  const int xcd = linear & 7;
  const int o = linear >> 3;              // per-XCD ordinal, 0..127
  const int m0 = (xcd * 16 + (o >> 3)) * 128;
  const int n0 = (o & 7) * 128;

  const int lrow = t >> 2;
  const int lcol = (t & 3) * 8;
  const short* gA0 = A + (size_t)(m0 + lrow) * K + lcol;
  const short* gB0 = Bt + (size_t)(n0 + lrow) * K + lcol;
  short* lA0 = &lsA[lrow * 32 + lcol];
  short* lB0 = &lsB[lrow * 32 + lcol];

  floatx4 acc[4][4];
#pragma unroll
  for (int i = 0; i < 4; ++i)
#pragma unroll
    for (int j = 0; j < 4; ++j) acc[i][j] = (floatx4){0.f, 0.f, 0.f, 0.f};

  for (int k0 = 0; k0 < K; k0 += 32) {
    load_lds16(gA0 + k0, lA0);
    load_lds16(gA0 + (size_t)64 * K + k0, lA0 + 64 * 32);
    load_lds16(gB0 + k0, lB0);
    load_lds16(gB0 + (size_t)64 * K + k0, lB0 + 64 * 32);
    __syncthreads();

    short8 af[4], bf[4];
#pragma unroll
    for (int mi = 0; mi < 4; ++mi)
      af[mi] = *(const short8*)&lsA[(wm * 64 + mi * 16 + lane16) * 32 + quad * 8];
#pragma unroll
    for (int ni = 0; ni < 4; ++ni)
      bf[ni] = *(const short8*)&lsB[(wn * 64 + ni * 16 + lane16) * 32 + quad * 8];

#pragma unroll
    for (int mi = 0; mi < 4; ++mi)
#pragma unroll
      for (int ni = 0; ni < 4; ++ni)
        acc[mi][ni] = __builtin_amdgcn_mfma_f32_16x16x32_bf16(af[mi], bf[ni], acc[mi][ni], 0, 0, 0);
    __syncthreads();
  }

  // epilogue: C/D layout col = lane&15, row = quad*4 + r  (m89/m91-verified)
#pragma unroll
  for (int mi = 0; mi < 4; ++mi) {
#pragma unroll
    for (int ni = 0; ni < 4; ++ni) {
      const int n = n0 + wn * 64 + ni * 16 + lane16;
      const float bv = bias[n];
#pragma unroll
      for (int r = 0; r < 4; ++r) {
        const int m = m0 + wm * 64 + mi * 16 + quad * 4 + r;
        out[(size_t)m * N + n] = acc[mi][ni][r] + bv;
      }
    }
  }
}

extern "C" void kernel_launch(void* const* d_in, const int* in_sizes, int n_in,
                              void* d_out, int out_size, void* d_ws, size_t ws_size,
                              hipStream_t stream) {
  const float* emb    = (const float*)d_in[0];  // (8, 4096, 768)
  const float* proj_w = (const float*)d_in[1];  // (768, 1024)
  const float* proj_b = (const float*)d_in[2];  // (1024,)
  const int*   masks  = (const int*)d_in[3];    // (8, 4096)
  const int*   wid    = (const int*)d_in[4];    // (8, 4096)

  float* out = (float*)d_out;                       // (8, 2048, 1024) fp32
  float* out_masks = out + (size_t)Bn * Wn * Dn;    // (8, 2048) as 0.0/1.0

  __hip_bfloat16* wb = (__hip_bfloat16*)d_ws;            // B^T: (1024, 768) bf16
  __hip_bfloat16* wa = wb + (size_t)Dn * Hn;             // A:   (16384, 768) bf16
  int* starts = (int*)(wa + (size_t)Bn * Wn * Hn);       // (8, 2049) boundaries

  // 1. fused: transpose proj_w + boundary table
  k_prep<<<dim3(768 + (Bn * Sn) / 256), 256, 0, stream>>>(proj_w, wid, wb, starts);

  // 2. segment means + masks (one wave per word)
  k_words<<<dim3(Wn / 4, Bn), 256, 0, stream>>>(emb, masks, starts, wa, out_masks);

  // 3. projection GEMM + bias (XCD-swizzled 1-D grid)
  k_gemm<<<dim3(1024), 256, 0, stream>>>((const short*)wa, (const short*)wb, proj_b, out);
}